// Round 3
// baseline (327.582 us; speedup 1.0000x reference)
//
#include <hip/hip_runtime.h>
#include <math.h>

// symLoss fused, occupancy-focused:
// grid = (B, C): batch b  ×  chunk c of the N samples. C=4 => 2048 blocks
// = 8 blocks/CU = 32 waves/CU (full occupancy) to hide scattered-gather
// latency (vol 4B + cp 12B at data-dependent voxel indices, L1/L2-served).
// Each thread owns ~1 point and does all 2*S evals (12 gathers in flight).
// cp gather as float3 -> one global_load_dwordx3. Block-reduce, 2 atomics.

#define NGRID3     32768            // 32^3
#define GRID_MIN_F (-0.484375f)     // -0.5 + 0.5/32
#define NTHREADS   256
#define NCHUNKS    4

__device__ __forceinline__ float point_loss(float x, float y, float z,
                                            const float* __restrict__ vol,
                                            const float* __restrict__ cp)
{
    // jnp: clip to [0,31] then round (nearest-even) => rintf after clamp
    float fx = fminf(fmaxf((x - GRID_MIN_F) * 32.0f, 0.0f), 31.0f);
    float fy = fminf(fmaxf((y - GRID_MIN_F) * 32.0f, 0.0f), 31.0f);
    float fz = fminf(fmaxf((z - GRID_MIN_F) * 32.0f, 0.0f), 31.0f);
    int lin = ((int)rintf(fx)) * 1024 + ((int)rintf(fy)) * 32 + (int)rintf(fz);

    float  m = 1.0f - vol[lin];
    float3 c = *(const float3*)(cp + lin * 3);
    float dx = (x - c.x) * m;
    float dy = (y - c.y) * m;
    float dz = (z - c.z) * m;
    return sqrtf(fmaxf(dx * dx + dy * dy + dz * dz, 1e-30f));
}

template <int S>
__global__ __launch_bounds__(NTHREADS) void symloss_fused(
    const float* __restrict__ planes,   // (S,B,4)
    const float* __restrict__ quats,    // (S,B,4)
    const float* __restrict__ cps,      // (B, 32768*3)
    const float* __restrict__ samples,  // (B,N,3)
    const float* __restrict__ volume,   // (B, 32768)
    float* __restrict__ out,            // 2 floats
    int B, int N, float scale)
{
    const int b     = blockIdx.x;
    const int chunk = (N + NCHUNKS - 1) / NCHUNKS;
    const int n0    = blockIdx.y * chunk;
    const int n1    = min(n0 + chunk, N);

    const float* __restrict__ vol = volume + (size_t)b * NGRID3;
    const float* __restrict__ cp  = cps    + (size_t)b * NGRID3 * 3;
    const float* __restrict__ sp  = samples + (size_t)b * N * 3;

    // per-s transform params in registers (S compile-time)
    float plx[S], ply[S], plz[S], plw[S], inv_n2[S];
    float qw[S], qx[S], qy[S], qz[S], w2mu[S];
#pragma unroll
    for (int s = 0; s < S; ++s) {
        float4 pl = ((const float4*)planes)[(size_t)s * B + b];
        float4 q  = ((const float4*)quats )[(size_t)s * B + b];
        plx[s] = pl.x; ply[s] = pl.y; plz[s] = pl.z; plw[s] = pl.w;
        inv_n2[s] = 1.0f / (pl.x * pl.x + pl.y * pl.y + pl.z * pl.z + 1e-8f);
        qw[s] = q.x; qx[s] = q.y; qy[s] = q.z; qz[s] = q.w;
        w2mu[s] = q.x * q.x - (q.y * q.y + q.z * q.z + q.w * q.w);
    }

    float sum_p = 0.0f, sum_q = 0.0f;
    for (int n = n0 + threadIdx.x; n < n1; n += NTHREADS) {
        const float3 p = *(const float3*)(sp + n * 3);
        const float px = p.x, py = p.y, pz = p.z;
#pragma unroll
        for (int s = 0; s < S; ++s) {
            // plane reflection
            float f = 2.0f * (px * plx[s] + py * ply[s] + pz * plz[s] + plw[s]) * inv_n2[s];
            sum_p += point_loss(px - f * plx[s], py - f * ply[s], pz - f * plz[s], vol, cp);

            // quaternion rotate (unnormalized): (w^2-|u|^2)p + 2(u.p)u + 2w(u x p)
            float udp = qx[s] * px + qy[s] * py + qz[s] * pz;
            float cx  = qy[s] * pz - qz[s] * py;
            float cy  = qz[s] * px - qx[s] * pz;
            float cz  = qx[s] * py - qy[s] * px;
            sum_q += point_loss(w2mu[s] * px + 2.0f * (udp * qx[s] + qw[s] * cx),
                                w2mu[s] * py + 2.0f * (udp * qy[s] + qw[s] * cy),
                                w2mu[s] * pz + 2.0f * (udp * qz[s] + qw[s] * cz),
                                vol, cp);
        }
    }

    // wave shuffle reduce (64-wide) then LDS across 4 waves
    for (int off = 32; off > 0; off >>= 1) {
        sum_p += __shfl_down(sum_p, off);
        sum_q += __shfl_down(sum_q, off);
    }
    __shared__ float red[NTHREADS / 64][2];
    const int lane = threadIdx.x & 63;
    const int wid  = threadIdx.x >> 6;
    if (lane == 0) { red[wid][0] = sum_p; red[wid][1] = sum_q; }
    __syncthreads();

    if (threadIdx.x == 0) {
        float tp = 0.0f, tq = 0.0f;
        for (int w = 0; w < NTHREADS / 64; ++w) { tp += red[w][0]; tq += red[w][1]; }
        atomicAdd(&out[0], tp * scale);
        atomicAdd(&out[1], tq * scale);
    }
}

extern "C" void kernel_launch(void* const* d_in, const int* in_sizes, int n_in,
                              void* d_out, int out_size, void* d_ws, size_t ws_size,
                              hipStream_t stream)
{
    const float* planes  = (const float*)d_in[0];
    const float* quats   = (const float*)d_in[1];
    const float* cps     = (const float*)d_in[2];
    const float* samples = (const float*)d_in[3];
    const float* volume  = (const float*)d_in[4];
    float* out = (float*)d_out;

    const int B = in_sizes[4] / NGRID3;     // 512
    const int S = in_sizes[0] / (B * 4);    // 3
    const int N = in_sizes[3] / (B * 3);    // 1000
    const float scale = 1.0f / (float)(S * B);

    hipMemsetAsync(d_out, 0, 2 * sizeof(float), stream);

    dim3 grid(B, NCHUNKS);
    switch (S) {
    case 1: symloss_fused<1><<<grid, NTHREADS, 0, stream>>>(planes, quats, cps, samples, volume, out, B, N, scale); break;
    case 2: symloss_fused<2><<<grid, NTHREADS, 0, stream>>>(planes, quats, cps, samples, volume, out, B, N, scale); break;
    case 3: symloss_fused<3><<<grid, NTHREADS, 0, stream>>>(planes, quats, cps, samples, volume, out, B, N, scale); break;
    case 4: symloss_fused<4><<<grid, NTHREADS, 0, stream>>>(planes, quats, cps, samples, volume, out, B, N, scale); break;
    default:
        for (int s = 0; s < S; ++s)
            symloss_fused<1><<<grid, NTHREADS, 0, stream>>>(planes + (size_t)s * B * 4,
                                                            quats  + (size_t)s * B * 4,
                                                            cps, samples, volume, out, B, N, scale);
        break;
    }
}